// Round 8
// baseline (318.578 us; speedup 1.0000x reference)
//
#include <hip/hip_runtime.h>
#include <hip/hip_bf16.h>

#define BB 4
#define TT 2048
#define DD 1024
#define NHEAD 16
#define HDIM 64

typedef __bf16 v8bf __attribute__((ext_vector_type(8)));
typedef __bf16 v4bf __attribute__((ext_vector_type(4)));
typedef float  v4f  __attribute__((ext_vector_type(4)));

// (1/32) * log2(e): folded into Q projection epilogue
#define C2SCALE 0.04508422376f

__device__ __forceinline__ void gl2lds16(const void* g, void* l) {
  __builtin_amdgcn_global_load_lds(
      (__attribute__((address_space(1))) const void*)g,
      (__attribute__((address_space(3))) void*)l, 16, 0, 0);
}

// ---------------------------------------------------------------------------
// prep: grid 2560.  (verbatim R4)
// ---------------------------------------------------------------------------
__global__ __launch_bounds__(256) void prep(
    const float* __restrict__ qsrc, const float* __restrict__ ksrc,
    const float* __restrict__ vsrc,
    const float* __restrict__ w0, const float* __restrict__ w1,
    const float* __restrict__ w2, const float* __restrict__ w3,
    __bf16* __restrict__ qdst, __bf16* __restrict__ kdst,
    __bf16* __restrict__ vdst,
    __bf16* __restrict__ t0, __bf16* __restrict__ t1,
    __bf16* __restrict__ t2, __bf16* __restrict__ t3) {
  constexpr int STR = 72;
  __shared__ __bf16 sh[64 * STR];
  int bx = blockIdx.x, tid = threadIdx.x;
  if (bx < 1536) {
    int z = bx >> 9, ib = bx & 511;
    const float* src = z == 0 ? qsrc : z == 1 ? ksrc : vsrc;
    __bf16* dst = z == 0 ? qdst : z == 1 ? kdst : vdst;
#pragma unroll
    for (int k = 0; k < 8; ++k) {
      int u = ib * 2048 + k * 256 + tid;           // 8-elem unit
      const float4* s = (const float4*)src + (size_t)u * 2;
      float4 f0 = s[0], f1 = s[1];
      v8bf v;
      v[0] = (__bf16)f0.x; v[1] = (__bf16)f0.y; v[2] = (__bf16)f0.z; v[3] = (__bf16)f0.w;
      v[4] = (__bf16)f1.x; v[5] = (__bf16)f1.y; v[6] = (__bf16)f1.z; v[7] = (__bf16)f1.w;
      *(v8bf*)(dst + (size_t)u * 8) = v;
    }
  } else {
    int idx = bx - 1536;
    int z = idx >> 8;
    const float* W = z == 0 ? w0 : z == 1 ? w1 : z == 2 ? w2 : w3;
    __bf16* Wt = z == 0 ? t0 : z == 1 ? t1 : z == 2 ? t2 : t3;
    int n0 = (idx & 15) * 64, k0 = ((idx >> 4) & 15) * 64;
#pragma unroll
    for (int p = 0; p < 4; ++p) {
      int c = tid + p * 256;
      int r = c >> 4, off = (c & 15) * 4;
      float4 f = *(const float4*)(W + (size_t)(k0 + r) * DD + n0 + off);
      __bf16* d = &sh[r * STR + off];
      d[0] = (__bf16)f.x; d[1] = (__bf16)f.y; d[2] = (__bf16)f.z; d[3] = (__bf16)f.w;
    }
    __syncthreads();
#pragma unroll
    for (int p = 0; p < 2; ++p) {
      int c = tid + p * 256;
      int nr = c >> 3, koff = (c & 7) * 8;
      v8bf v;
#pragma unroll
      for (int j = 0; j < 8; ++j) v[j] = sh[(koff + j) * STR + nr];
      *(v8bf*)(Wt + (size_t)(n0 + nr) * DD + k0 + koff) = v;
    }
  }
}

// ---------------------------------------------------------------------------
// Shared GEMM mainloop (proven R0/R4 structure).
// ---------------------------------------------------------------------------
__device__ __forceinline__ void gemm_core(const __bf16* __restrict__ A,
                                          const __bf16* __restrict__ Wt,
                                          int m0, int n0,
                                          __bf16* ash, __bf16* bsh,
                                          int wave, int lane, int quad, int l15,
                                          v4f acc[4][4]) {
  int wm = (wave & 1) * 64, wn = (wave >> 1) * 64;
  for (int k0 = 0; k0 < DD; k0 += 64) {
    __syncthreads();
#pragma unroll
    for (int i = 0; i < 4; ++i) {
      int c = wave * 256 + i * 64 + lane;
      int row = c >> 3, g = (c & 7) ^ (row & 7);
      gl2lds16(A + (size_t)(m0 + row) * DD + k0 + g * 8, ash + wave * 2048 + i * 512);
      gl2lds16(Wt + (size_t)(n0 + row) * DD + k0 + g * 8, bsh + wave * 2048 + i * 512);
    }
    __syncthreads();
#pragma unroll
    for (int ks = 0; ks < 2; ++ks) {
      int sw = (((ks * 4 + quad) ^ (l15 & 7))) * 8;
      v8bf a[4], b[4];
#pragma unroll
      for (int jm = 0; jm < 4; ++jm) a[jm] = *(v8bf*)&ash[(wm + jm * 16 + l15) * 64 + sw];
#pragma unroll
      for (int jn = 0; jn < 4; ++jn) b[jn] = *(v8bf*)&bsh[(wn + jn * 16 + l15) * 64 + sw];
#pragma unroll
      for (int jm = 0; jm < 4; ++jm)
#pragma unroll
        for (int jn = 0; jn < 4; ++jn)
          acc[jm][jn] = __builtin_amdgcn_mfma_f32_16x16x32_bf16(a[jm], b[jn], acc[jm][jn], 0, 0, 0);
    }
  }
}

// XCD-aware tile swizzle: the 8 blocks sharing an m-panel get lin%8==c -> one XCD.
__device__ __forceinline__ void swz_tiles(int& m0, int& n0) {
  int lin = blockIdx.x + 8 * blockIdx.y;
  int c = lin & 7, t = lin >> 3;
  n0 = (t & 7) * 128;
  m0 = (c + ((t >> 3) << 3)) * 128;
}

// ---------------------------------------------------------------------------
// Fused Q/K/V projection GEMMs. grid (8,64,3).  (verbatim R4)
// ---------------------------------------------------------------------------
__global__ __launch_bounds__(256) void gemm_qkv(
    const __bf16* __restrict__ Qc, const __bf16* __restrict__ Kc,
    const __bf16* __restrict__ Vc,
    const __bf16* __restrict__ wqT, const __bf16* __restrict__ wkT,
    const __bf16* __restrict__ wvT,
    const float* __restrict__ qb, const float* __restrict__ kb,
    const float* __restrict__ vb,
    __bf16* __restrict__ Qp, __bf16* __restrict__ Kp, __bf16* __restrict__ VTb) {
  __shared__ __bf16 ash[128 * 64];
  __shared__ __bf16 bsh[128 * 64];
  int z = blockIdx.z;
  const __bf16* A  = z == 0 ? Qc : z == 1 ? Kc : Vc;
  const __bf16* Wt = z == 0 ? wqT : z == 1 ? wkT : wvT;
  const float* bias = z == 0 ? qb : z == 1 ? kb : vb;
  int tid = threadIdx.x, wave = tid >> 6, lane = tid & 63;
  int quad = lane >> 4, l15 = lane & 15;
  int m0, n0;
  swz_tiles(m0, n0);
  int wm = (wave & 1) * 64, wn = (wave >> 1) * 64;
  v4f acc[4][4];
#pragma unroll
  for (int jm = 0; jm < 4; ++jm)
#pragma unroll
    for (int jn = 0; jn < 4; ++jn) acc[jm][jn] = (v4f){0.f, 0.f, 0.f, 0.f};

  gemm_core(A, Wt, m0, n0, ash, bsh, wave, lane, quad, l15, acc);

  if (z == 2) {
    int b = m0 >> 11;
    int tbase = (m0 & 2047) + wm;
#pragma unroll
    for (int jn = 0; jn < 4; ++jn) {
      int col = n0 + wn + jn * 16 + l15;   // = h*64 + d
      float bv = bias[col];
      __bf16* rowp = VTb + ((size_t)(b * 16 + (col >> 6)) * 64 + (col & 63)) * TT;
#pragma unroll
      for (int jm = 0; jm < 4; ++jm) {
        v4bf o;
#pragma unroll
        for (int r = 0; r < 4; ++r) o[r] = (__bf16)(acc[jm][jn][r] + bv);
        *(v4bf*)(rowp + tbase + jm * 16 + quad * 4) = o;
      }
    }
  } else {
    __bf16* C = z == 0 ? Qp : Kp;
    float scale = z == 0 ? C2SCALE : 1.0f;
#pragma unroll
    for (int jn = 0; jn < 4; ++jn) {
      int col = n0 + wn + jn * 16 + l15;
      float bv = bias[col];
#pragma unroll
      for (int jm = 0; jm < 4; ++jm) {
#pragma unroll
        for (int r = 0; r < 4; ++r) {
          int row = m0 + wm + jm * 16 + quad * 4 + r;
          C[(size_t)row * DD + col] = (__bf16)((acc[jm][jn][r] + bv) * scale);
        }
      }
    }
  }
}

// ---------------------------------------------------------------------------
// Output GEMM: out = Ab @ woT^T + wo_b (fp32). grid (8,64).  (verbatim R4)
// ---------------------------------------------------------------------------
__global__ __launch_bounds__(256) void gemm_out(const __bf16* __restrict__ A,
                                                const __bf16* __restrict__ Wt,
                                                const float* __restrict__ bias,
                                                float* __restrict__ C) {
  __shared__ __bf16 ash[128 * 64];
  __shared__ __bf16 bsh[128 * 64];
  int tid = threadIdx.x, wave = tid >> 6, lane = tid & 63;
  int quad = lane >> 4, l15 = lane & 15;
  int m0, n0;
  swz_tiles(m0, n0);
  int wm = (wave & 1) * 64, wn = (wave >> 1) * 64;
  v4f acc[4][4];
#pragma unroll
  for (int jm = 0; jm < 4; ++jm)
#pragma unroll
    for (int jn = 0; jn < 4; ++jn) acc[jm][jn] = (v4f){0.f, 0.f, 0.f, 0.f};

  gemm_core(A, Wt, m0, n0, ash, bsh, wave, lane, quad, l15, acc);

#pragma unroll
  for (int jn = 0; jn < 4; ++jn) {
    int col = n0 + wn + jn * 16 + l15;
    float bv = bias[col];
#pragma unroll
    for (int jm = 0; jm < 4; ++jm) {
#pragma unroll
      for (int r = 0; r < 4; ++r) {
        int row = m0 + wm + jm * 16 + quad * 4 + r;
        C[(size_t)row * DD + col] = acc[jm][jn][r] + bv;
      }
    }
  }
}

// ---------------------------------------------------------------------------
// Flash attention (causal), transposed-softmax, lr via ones-MFMA, setprio,
// dbuf K/V — R7-proven k-loop body.
// NEW: 256 q-rows per block (64/wave, 4 sets).  K/V fragments are hoisted to
// registers ONCE per k-tile and reused across all 4 sets -> LDS traffic per
// unit of work drops ~36% (attn was LDS-BW-bound: 4 waves re-reading full
// K/V tiles saturated the LDS pipe at 3 blocks/CU).
// grid (8,64) = 512 blocks = exactly 2/CU, all co-resident (64KB dynamic LDS,
// VGPR<=256 via __launch_bounds__(256,2); QK^T done in 2 set-pairs to bound
// live range).  Load balance: resident pairs are (y, y+32) under
// order-respecting dispatch; qi mapping makes each pair sum to 36 k-tiles.
// XCD affinity: bh = c + 8*(y&7) keeps 8 heads/XCD = 4MB K+V in L2.
// ---------------------------------------------------------------------------
__global__ __launch_bounds__(256, 2) void attn_bal(const __bf16* __restrict__ Q,
                                                   const __bf16* __restrict__ K,
                                                   const __bf16* __restrict__ VT,
                                                   __bf16* __restrict__ O) {
  extern __shared__ __bf16 lds[];
  __bf16* ksh = lds;              // [2][64*64]
  __bf16* vsh = lds + 8192;      // [2][64*64]  vsh[d][t]
  __bf16* psh = lds + 16384;     // [256*64]  Q staging / P^T, XOR-swizzled
  int tid = threadIdx.x, wave = tid >> 6, lane = tid & 63;
  int quad = lane >> 4, l15 = lane & 15;
  int swz = l15 & 7;
  int c = blockIdx.x;                 // XCD slot 0..7
  int y = blockIdx.y;                 // 0..63
  int bh = c + 8 * (y & 7);           // head-group 0..63
  int yy = y >> 3;                    // 0..7
  int qi = yy < 4 ? 7 - yy : yy - 4;  // pairs (y,y+32) sum to 7; longest first
  int b = bh >> 4, h = bh & 15;
  const __bf16* Qb = Q + (size_t)(b * TT) * DD + h * HDIM;
  const __bf16* Kb = K + (size_t)(b * TT) * DD + h * HDIM;
  const __bf16* Vb = VT + (size_t)bh * HDIM * TT;
  __bf16* Ob = O + (size_t)(b * TT) * DD + h * HDIM;

  v8bf ones;
#pragma unroll
  for (int j = 0; j < 8; ++j) ones[j] = (__bf16)1.0f;

  int q0 = qi * 256;
  int ktiles = 4 * qi + 4;

  // stage this wave's own 64 Q rows (wave-private psh region, 8 rounds)
#pragma unroll
  for (int i = 0; i < 8; ++i) {
    int cc = wave * 512 + i * 64 + lane;
    int row = cc >> 3, g = (cc & 7) ^ (row & 7);
    gl2lds16(Qb + (size_t)(q0 + row) * DD + g * 8, psh + wave * 4096 + i * 512);
  }
  // stage k-tile 0 into buffer 0
#pragma unroll
  for (int i = 0; i < 2; ++i) {
    int cc = wave * 128 + i * 64 + lane;
    int row = cc >> 3, g = (cc & 7) ^ (row & 7);
    gl2lds16(Kb + (size_t)row * DD + g * 8, ksh + wave * 1024 + i * 512);
    gl2lds16(Vb + (size_t)row * TT + g * 8, vsh + wave * 1024 + i * 512);
  }
  __builtin_amdgcn_s_waitcnt(0);
  __syncthreads();

  // hoist Q fragments (B-operand) for the entire k-loop
  v8bf qf[4][2];
#pragma unroll
  for (int set = 0; set < 4; ++set)
#pragma unroll
    for (int ks = 0; ks < 2; ++ks)
      qf[set][ks] = *(v8bf*)&psh[(wave * 64 + set * 16 + l15) * 64 + ((ks * 4 + quad) ^ swz) * 8];

  int qg[4];
#pragma unroll
  for (int set = 0; set < 4; ++set) qg[set] = q0 + wave * 64 + set * 16 + l15;
  v4f oacc[4][4], lracc[4];
#pragma unroll
  for (int set = 0; set < 4; ++set) {
    lracc[set] = (v4f){0.f, 0.f, 0.f, 0.f};
#pragma unroll
    for (int jm = 0; jm < 4; ++jm) oacc[set][jm] = (v4f){0.f, 0.f, 0.f, 0.f};
  }

  int pbuf = 0;
  for (int kt = 0; kt < ktiles; ++kt) {
    // prefetch next k-tile into the other buffer; completes during compute
    if (kt + 1 < ktiles) {
      int k0n = (kt + 1) * 64;
#pragma unroll
      for (int i = 0; i < 2; ++i) {
        int cc = wave * 128 + i * 64 + lane;
        int row = cc >> 3, g = (cc & 7) ^ (row & 7);
        gl2lds16(Kb + (size_t)(k0n + row) * DD + g * 8,
                 ksh + (pbuf ^ 1) * 4096 + wave * 1024 + i * 512);
        gl2lds16(Vb + (size_t)row * TT + k0n + g * 8,
                 vsh + (pbuf ^ 1) * 4096 + wave * 1024 + i * 512);
      }
    }
    int k0 = kt * 64;
    const __bf16* kshp = ksh + pbuf * 4096;
    const __bf16* vshp = vsh + pbuf * 4096;

    // hoist K fragments once; reuse for all 4 sets
    v8bf kf[2][4];
#pragma unroll
    for (int ks = 0; ks < 2; ++ks) {
      int sw = ((ks * 4 + quad) ^ swz) * 8;
#pragma unroll
      for (int jf = 0; jf < 4; ++jf)
        kf[ks][jf] = *(v8bf*)&kshp[(jf * 16 + l15) * 64 + sw];
    }

    bool diag = (kt >= 4 * qi);
    // S^T = K (C2*Q)^T in two set-pairs (bounds live VGPRs)
#pragma unroll
    for (int sp = 0; sp < 2; ++sp) {
      v4f s[2][4];
#pragma unroll
      for (int ss = 0; ss < 2; ++ss)
#pragma unroll
        for (int jf = 0; jf < 4; ++jf) s[ss][jf] = (v4f){0.f, 0.f, 0.f, 0.f};
      __builtin_amdgcn_s_setprio(1);
#pragma unroll
      for (int ks = 0; ks < 2; ++ks)
#pragma unroll
        for (int jf = 0; jf < 4; ++jf) {
          s[0][jf] = __builtin_amdgcn_mfma_f32_16x16x32_bf16(kf[ks][jf], qf[sp * 2][ks], s[0][jf], 0, 0, 0);
          s[1][jf] = __builtin_amdgcn_mfma_f32_16x16x32_bf16(kf[ks][jf], qf[sp * 2 + 1][ks], s[1][jf], 0, 0, 0);
        }
      __builtin_amdgcn_s_setprio(0);

#pragma unroll
      for (int ss = 0; ss < 2; ++ss) {
        int set = sp * 2 + ss;
        int qrow = wave * 64 + set * 16 + l15;
        __bf16* prow = &psh[qrow * 64];
#pragma unroll
        for (int jf = 0; jf < 4; ++jf) {
          v4bf pk;
#pragma unroll
          for (int r = 0; r < 4; ++r) {
            float p = __builtin_amdgcn_exp2f(s[ss][jf][r]);
            if (diag) {
              int kg = k0 + jf * 16 + quad * 4 + r;
              if (kg > qg[set]) p = 0.f;
            }
            pk[r] = (__bf16)p;
          }
          int chunk = jf * 2 + (quad >> 1);
          *(v4bf*)&prow[(chunk ^ swz) * 8 + (quad & 1) * 4] = pk;
        }
      }
    }

    // O^T += V^T P^T ; lr += ones @ P^T.  V fragments loaded once per ks,
    // reused by all 4 sets.
    __builtin_amdgcn_s_setprio(1);
#pragma unroll
    for (int ks = 0; ks < 2; ++ks) {
      int sw = ((ks * 4 + quad) ^ swz) * 8;
      v8bf pb[4];
#pragma unroll
      for (int set = 0; set < 4; ++set)
        pb[set] = *(v8bf*)&psh[(wave * 64 + set * 16 + l15) * 64 + sw];
#pragma unroll
      for (int set = 0; set < 4; ++set)
        lracc[set] = __builtin_amdgcn_mfma_f32_16x16x32_bf16(ones, pb[set], lracc[set], 0, 0, 0);
#pragma unroll
      for (int jm = 0; jm < 4; ++jm) {
        v8bf vf = *(v8bf*)&vshp[(jm * 16 + l15) * 64 + sw];
#pragma unroll
        for (int set = 0; set < 4; ++set)
          oacc[set][jm] = __builtin_amdgcn_mfma_f32_16x16x32_bf16(vf, pb[set], oacc[set][jm], 0, 0, 0);
      }
    }
    __builtin_amdgcn_s_setprio(0);

    __builtin_amdgcn_s_waitcnt(0);   // own next-tile DMA long since done
    __syncthreads();
    pbuf ^= 1;
  }

  // epilogue: O[q][d] = O^T / lr
#pragma unroll
  for (int set = 0; set < 4; ++set) {
    float inv = 1.0f / lracc[set][0];
    int q = q0 + wave * 64 + set * 16 + l15;
#pragma unroll
    for (int jm = 0; jm < 4; ++jm) {
      v4bf o;
#pragma unroll
      for (int r = 0; r < 4; ++r) o[r] = (__bf16)(oacc[set][jm][r] * inv);
      *(v4bf*)(Ob + (size_t)q * DD + jm * 16 + quad * 4) = o;
    }
  }
}

// ---------------------------------------------------------------------------
extern "C" void kernel_launch(void* const* d_in, const int* in_sizes, int n_in,
                              void* d_out, int out_size, void* d_ws, size_t ws_size,
                              hipStream_t stream) {
  const float* query = (const float*)d_in[0];
  const float* key_  = (const float*)d_in[1];
  const float* value = (const float*)d_in[2];
  const float* wq_w = (const float*)d_in[3];
  const float* wq_b = (const float*)d_in[4];
  const float* wk_w = (const float*)d_in[5];
  const float* wk_b = (const float*)d_in[6];
  const float* wv_w = (const float*)d_in[7];
  const float* wv_b = (const float*)d_in[8];
  const float* wo_w = (const float*)d_in[9];
  const float* wo_b = (const float*)d_in[10];

  char* ws = (char*)d_ws;
  const size_t MB = (size_t)1 << 20;
  __bf16* wqT = (__bf16*)(ws + 0 * MB);
  __bf16* wkT = (__bf16*)(ws + 2 * MB);
  __bf16* wvT = (__bf16*)(ws + 4 * MB);
  __bf16* woT = (__bf16*)(ws + 6 * MB);
  __bf16* Qc  = (__bf16*)(ws + 8 * MB);    // cast inputs (later reused)
  __bf16* Kc  = (__bf16*)(ws + 24 * MB);
  __bf16* Vc  = (__bf16*)(ws + 40 * MB);
  __bf16* Qp  = (__bf16*)(ws + 56 * MB);
  __bf16* Kp  = (__bf16*)(ws + 72 * MB);
  __bf16* VTb = (__bf16*)(ws + 88 * MB);   // peak 104 MB
  __bf16* Ab  = (__bf16*)(ws + 8 * MB);    // reuse Qc
  float* out = (float*)d_out;

  static int attr_done = 0;
  if (!attr_done) {
    hipFuncSetAttribute((const void*)attn_bal,
                        hipFuncAttributeMaxDynamicSharedMemorySize, 65536);
    attr_done = 1;
  }

  dim3 tb(256);
  prep<<<dim3(2560), tb, 0, stream>>>(query, key_, value, wq_w, wk_w, wv_w, wo_w,
                                      Qc, Kc, Vc, wqT, wkT, wvT, woT);
  gemm_qkv<<<dim3(8, 64, 3), tb, 0, stream>>>(Qc, Kc, Vc, wqT, wkT, wvT,
                                              wq_b, wk_b, wv_b, Qp, Kp, VTb);
  attn_bal<<<dim3(8, 64), tb, 65536, stream>>>(Qp, Kp, VTb, Ab);
  gemm_out<<<dim3(8, 64), tb, 0, stream>>>(Ab, woT, wo_b, out);
}

// Round 9
// 311.225 us; speedup vs baseline: 1.0236x; 1.0236x over previous
//
#include <hip/hip_runtime.h>
#include <hip/hip_bf16.h>

#define BB 4
#define TT 2048
#define DD 1024
#define NHEAD 16
#define HDIM 64

typedef __bf16 v8bf __attribute__((ext_vector_type(8)));
typedef __bf16 v4bf __attribute__((ext_vector_type(4)));
typedef float  v4f  __attribute__((ext_vector_type(4)));

// (1/32) * log2(e): folded into Q projection epilogue
#define C2SCALE 0.04508422376f

__device__ __forceinline__ void gl2lds16(const void* g, void* l) {
  __builtin_amdgcn_global_load_lds(
      (__attribute__((address_space(1))) const void*)g,
      (__attribute__((address_space(3))) void*)l, 16, 0, 0);
}

// ---------------------------------------------------------------------------
// prep: grid 2560.
//   blocks 0..1535:   fp32->bf16 casts, 8 x (256x8-elem) units per block
//   blocks 1536..2559: 4 weight transposes, 64x64 tiles
// ---------------------------------------------------------------------------
__global__ __launch_bounds__(256) void prep(
    const float* __restrict__ qsrc, const float* __restrict__ ksrc,
    const float* __restrict__ vsrc,
    const float* __restrict__ w0, const float* __restrict__ w1,
    const float* __restrict__ w2, const float* __restrict__ w3,
    __bf16* __restrict__ qdst, __bf16* __restrict__ kdst,
    __bf16* __restrict__ vdst,
    __bf16* __restrict__ t0, __bf16* __restrict__ t1,
    __bf16* __restrict__ t2, __bf16* __restrict__ t3) {
  constexpr int STR = 72;
  __shared__ __bf16 sh[64 * STR];
  int bx = blockIdx.x, tid = threadIdx.x;
  if (bx < 1536) {
    int z = bx >> 9, ib = bx & 511;
    const float* src = z == 0 ? qsrc : z == 1 ? ksrc : vsrc;
    __bf16* dst = z == 0 ? qdst : z == 1 ? kdst : vdst;
#pragma unroll
    for (int k = 0; k < 8; ++k) {
      int u = ib * 2048 + k * 256 + tid;           // 8-elem unit
      const float4* s = (const float4*)src + (size_t)u * 2;
      float4 f0 = s[0], f1 = s[1];
      v8bf v;
      v[0] = (__bf16)f0.x; v[1] = (__bf16)f0.y; v[2] = (__bf16)f0.z; v[3] = (__bf16)f0.w;
      v[4] = (__bf16)f1.x; v[5] = (__bf16)f1.y; v[6] = (__bf16)f1.z; v[7] = (__bf16)f1.w;
      *(v8bf*)(dst + (size_t)u * 8) = v;
    }
  } else {
    int idx = bx - 1536;
    int z = idx >> 8;
    const float* W = z == 0 ? w0 : z == 1 ? w1 : z == 2 ? w2 : w3;
    __bf16* Wt = z == 0 ? t0 : z == 1 ? t1 : z == 2 ? t2 : t3;
    int n0 = (idx & 15) * 64, k0 = ((idx >> 4) & 15) * 64;
#pragma unroll
    for (int p = 0; p < 4; ++p) {
      int c = tid + p * 256;
      int r = c >> 4, off = (c & 15) * 4;
      float4 f = *(const float4*)(W + (size_t)(k0 + r) * DD + n0 + off);
      __bf16* d = &sh[r * STR + off];
      d[0] = (__bf16)f.x; d[1] = (__bf16)f.y; d[2] = (__bf16)f.z; d[3] = (__bf16)f.w;
    }
    __syncthreads();
#pragma unroll
    for (int p = 0; p < 2; ++p) {
      int c = tid + p * 256;
      int nr = c >> 3, koff = (c & 7) * 8;
      v8bf v;
#pragma unroll
      for (int j = 0; j < 8; ++j) v[j] = sh[(koff + j) * STR + nr];
      *(v8bf*)(Wt + (size_t)(n0 + nr) * DD + k0 + koff) = v;
    }
  }
}

// ---------------------------------------------------------------------------
// Shared GEMM mainloop: acc[4][4] += A-tile(m0) @ Wt-tile(n0)^T over K=1024.
// (proven R0/R4 structure — every structural variant tried in R1/R2/R5 lost)
// ---------------------------------------------------------------------------
__device__ __forceinline__ void gemm_core(const __bf16* __restrict__ A,
                                          const __bf16* __restrict__ Wt,
                                          int m0, int n0,
                                          __bf16* ash, __bf16* bsh,
                                          int wave, int lane, int quad, int l15,
                                          v4f acc[4][4]) {
  int wm = (wave & 1) * 64, wn = (wave >> 1) * 64;
  for (int k0 = 0; k0 < DD; k0 += 64) {
    __syncthreads();
#pragma unroll
    for (int i = 0; i < 4; ++i) {
      int c = wave * 256 + i * 64 + lane;
      int row = c >> 3, g = (c & 7) ^ (row & 7);
      gl2lds16(A + (size_t)(m0 + row) * DD + k0 + g * 8, ash + wave * 2048 + i * 512);
      gl2lds16(Wt + (size_t)(n0 + row) * DD + k0 + g * 8, bsh + wave * 2048 + i * 512);
    }
    __syncthreads();
#pragma unroll
    for (int ks = 0; ks < 2; ++ks) {
      int sw = (((ks * 4 + quad) ^ (l15 & 7))) * 8;
      v8bf a[4], b[4];
#pragma unroll
      for (int jm = 0; jm < 4; ++jm) a[jm] = *(v8bf*)&ash[(wm + jm * 16 + l15) * 64 + sw];
#pragma unroll
      for (int jn = 0; jn < 4; ++jn) b[jn] = *(v8bf*)&bsh[(wn + jn * 16 + l15) * 64 + sw];
#pragma unroll
      for (int jm = 0; jm < 4; ++jm)
#pragma unroll
        for (int jn = 0; jn < 4; ++jn)
          acc[jm][jn] = __builtin_amdgcn_mfma_f32_16x16x32_bf16(a[jm], b[jn], acc[jm][jn], 0, 0, 0);
    }
  }
}

// XCD-aware tile swizzle: the 8 blocks sharing an m-panel get lin%8==c -> one XCD.
__device__ __forceinline__ void swz_tiles(int& m0, int& n0) {
  int lin = blockIdx.x + 8 * blockIdx.y;
  int c = lin & 7, t = lin >> 3;
  n0 = (t & 7) * 128;
  m0 = (c + ((t >> 3) << 3)) * 128;
}

// ---------------------------------------------------------------------------
// Fused Q/K/V projection GEMMs. grid (8,64,3).  (verbatim R4)
// ---------------------------------------------------------------------------
__global__ __launch_bounds__(256) void gemm_qkv(
    const __bf16* __restrict__ Qc, const __bf16* __restrict__ Kc,
    const __bf16* __restrict__ Vc,
    const __bf16* __restrict__ wqT, const __bf16* __restrict__ wkT,
    const __bf16* __restrict__ wvT,
    const float* __restrict__ qb, const float* __restrict__ kb,
    const float* __restrict__ vb,
    __bf16* __restrict__ Qp, __bf16* __restrict__ Kp, __bf16* __restrict__ VTb) {
  __shared__ __bf16 ash[128 * 64];
  __shared__ __bf16 bsh[128 * 64];
  int z = blockIdx.z;
  const __bf16* A  = z == 0 ? Qc : z == 1 ? Kc : Vc;
  const __bf16* Wt = z == 0 ? wqT : z == 1 ? wkT : wvT;
  const float* bias = z == 0 ? qb : z == 1 ? kb : vb;
  int tid = threadIdx.x, wave = tid >> 6, lane = tid & 63;
  int quad = lane >> 4, l15 = lane & 15;
  int m0, n0;
  swz_tiles(m0, n0);
  int wm = (wave & 1) * 64, wn = (wave >> 1) * 64;
  v4f acc[4][4];
#pragma unroll
  for (int jm = 0; jm < 4; ++jm)
#pragma unroll
    for (int jn = 0; jn < 4; ++jn) acc[jm][jn] = (v4f){0.f, 0.f, 0.f, 0.f};

  gemm_core(A, Wt, m0, n0, ash, bsh, wave, lane, quad, l15, acc);

  if (z == 2) {
    int b = m0 >> 11;
    int tbase = (m0 & 2047) + wm;
#pragma unroll
    for (int jn = 0; jn < 4; ++jn) {
      int col = n0 + wn + jn * 16 + l15;   // = h*64 + d
      float bv = bias[col];
      __bf16* rowp = VTb + ((size_t)(b * 16 + (col >> 6)) * 64 + (col & 63)) * TT;
#pragma unroll
      for (int jm = 0; jm < 4; ++jm) {
        v4bf o;
#pragma unroll
        for (int r = 0; r < 4; ++r) o[r] = (__bf16)(acc[jm][jn][r] + bv);
        *(v4bf*)(rowp + tbase + jm * 16 + quad * 4) = o;
      }
    }
  } else {
    __bf16* C = z == 0 ? Qp : Kp;
    float scale = z == 0 ? C2SCALE : 1.0f;
#pragma unroll
    for (int jn = 0; jn < 4; ++jn) {
      int col = n0 + wn + jn * 16 + l15;
      float bv = bias[col];
#pragma unroll
      for (int jm = 0; jm < 4; ++jm) {
#pragma unroll
        for (int r = 0; r < 4; ++r) {
          int row = m0 + wm + jm * 16 + quad * 4 + r;
          C[(size_t)row * DD + col] = (__bf16)((acc[jm][jn][r] + bv) * scale);
        }
      }
    }
  }
}

// ---------------------------------------------------------------------------
// Output GEMM: out = Ab @ woT^T + wo_b (fp32). grid (8,64).  (verbatim R4)
// ---------------------------------------------------------------------------
__global__ __launch_bounds__(256) void gemm_out(const __bf16* __restrict__ A,
                                                const __bf16* __restrict__ Wt,
                                                const float* __restrict__ bias,
                                                float* __restrict__ C) {
  __shared__ __bf16 ash[128 * 64];
  __shared__ __bf16 bsh[128 * 64];
  int tid = threadIdx.x, wave = tid >> 6, lane = tid & 63;
  int quad = lane >> 4, l15 = lane & 15;
  int m0, n0;
  swz_tiles(m0, n0);
  int wm = (wave & 1) * 64, wn = (wave >> 1) * 64;
  v4f acc[4][4];
#pragma unroll
  for (int jm = 0; jm < 4; ++jm)
#pragma unroll
    for (int jn = 0; jn < 4; ++jn) acc[jm][jn] = (v4f){0.f, 0.f, 0.f, 0.f};

  gemm_core(A, Wt, m0, n0, ash, bsh, wave, lane, quad, l15, acc);

#pragma unroll
  for (int jn = 0; jn < 4; ++jn) {
    int col = n0 + wn + jn * 16 + l15;
    float bv = bias[col];
#pragma unroll
    for (int jm = 0; jm < 4; ++jm) {
#pragma unroll
      for (int r = 0; r < 4; ++r) {
        int row = m0 + wm + jm * 16 + quad * 4 + r;
        C[(size_t)row * DD + col] = acc[jm][jn][r] + bv;
      }
    }
  }
}

// ---------------------------------------------------------------------------
// Flash attention (causal), transposed-softmax, no running max, lr via
// ones-MFMA, setprio, dbuf K/V — the R7-proven configuration (session best):
// ONE q-tile per block, grid (8,128) = 1024 blocks -> 3 blocks/CU resident
// (48KB LDS x3 = 144KB <= 160KB).  Long blocks (qi=15) launch first via
// qi = 15-(by>>3); XCD affinity bh = c + 8*(by&7) keeps 8 heads/XCD = 4MB
// K+V in L2.  R8's 256-row variant (2/CU, hoisted K/V frags) regressed —
// the extra resident block is the proven mechanism, keep 3/CU.
// ---------------------------------------------------------------------------
__global__ __launch_bounds__(256) void attn_bal(const __bf16* __restrict__ Q,
                                                const __bf16* __restrict__ K,
                                                const __bf16* __restrict__ VT,
                                                __bf16* __restrict__ O) {
  __shared__ __bf16 ksh[2][64 * 64];
  __shared__ __bf16 vsh[2][64 * 64];       // vsh[d][t]
  __shared__ __bf16 psh[128 * 64];         // Q staging / P^T, XOR-swizzled
  int tid = threadIdx.x, wave = tid >> 6, lane = tid & 63;
  int quad = lane >> 4, l15 = lane & 15;
  int swz = l15 & 7;
  int c = blockIdx.x;                 // XCD slot 0..7
  int by = blockIdx.y;                // 0..127
  int bh = c + 8 * (by & 7);          // head-group 0..63
  int qi = 15 - (by >> 3);            // q-tile 15..0 (longest first)
  int b = bh >> 4, h = bh & 15;
  const __bf16* Qb = Q + (size_t)(b * TT) * DD + h * HDIM;
  const __bf16* Kb = K + (size_t)(b * TT) * DD + h * HDIM;
  const __bf16* Vb = VT + (size_t)bh * HDIM * TT;
  __bf16* Ob = O + (size_t)(b * TT) * DD + h * HDIM;

  v8bf ones;
#pragma unroll
  for (int j = 0; j < 8; ++j) ones[j] = (__bf16)1.0f;

  int q0 = qi * 128;
  int ktiles = 2 * qi + 2;

  // stage this wave's own Q rows (wave-private psh region)
#pragma unroll
  for (int i = 0; i < 4; ++i) {
    int cc = wave * 256 + i * 64 + lane;
    int row = cc >> 3, g = (cc & 7) ^ (row & 7);
    gl2lds16(Qb + (size_t)(q0 + row) * DD + g * 8, psh + wave * 2048 + i * 512);
  }
  // stage k-tile 0 into buffer 0
#pragma unroll
  for (int i = 0; i < 2; ++i) {
    int cc = wave * 128 + i * 64 + lane;
    int row = cc >> 3, g = (cc & 7) ^ (row & 7);
    gl2lds16(Kb + (size_t)row * DD + g * 8, &ksh[0][wave * 1024 + i * 512]);
    gl2lds16(Vb + (size_t)row * TT + g * 8, &vsh[0][wave * 1024 + i * 512]);
  }
  __builtin_amdgcn_s_waitcnt(0);
  __syncthreads();

  // hoist Q fragments (B-operand) for the entire k-loop
  v8bf qf[2][2];
#pragma unroll
  for (int set = 0; set < 2; ++set)
#pragma unroll
    for (int ks = 0; ks < 2; ++ks)
      qf[set][ks] = *(v8bf*)&psh[(wave * 32 + set * 16 + l15) * 64 + ((ks * 4 + quad) ^ swz) * 8];

  int qg[2] = {q0 + wave * 32 + l15, q0 + wave * 32 + 16 + l15};
  v4f oacc[2][4], lracc[2];
#pragma unroll
  for (int set = 0; set < 2; ++set) {
    lracc[set] = (v4f){0.f, 0.f, 0.f, 0.f};
#pragma unroll
    for (int jm = 0; jm < 4; ++jm) oacc[set][jm] = (v4f){0.f, 0.f, 0.f, 0.f};
  }

  int pbuf = 0;
  for (int kt = 0; kt < ktiles; ++kt) {
    // prefetch next k-tile into the other buffer; completes during compute
    if (kt + 1 < ktiles) {
      int k0n = (kt + 1) * 64;
#pragma unroll
      for (int i = 0; i < 2; ++i) {
        int cc = wave * 128 + i * 64 + lane;
        int row = cc >> 3, g = (cc & 7) ^ (row & 7);
        gl2lds16(Kb + (size_t)(k0n + row) * DD + g * 8, &ksh[pbuf ^ 1][wave * 1024 + i * 512]);
        gl2lds16(Vb + (size_t)row * TT + k0n + g * 8, &vsh[pbuf ^ 1][wave * 1024 + i * 512]);
      }
    }
    int k0 = kt * 64;
    const __bf16* kshp = &ksh[pbuf][0];
    const __bf16* vshp = &vsh[pbuf][0];

    // S^T = K (C2*Q)^T
    v4f s[2][4];
#pragma unroll
    for (int set = 0; set < 2; ++set)
#pragma unroll
      for (int jf = 0; jf < 4; ++jf) s[set][jf] = (v4f){0.f, 0.f, 0.f, 0.f};
    __builtin_amdgcn_s_setprio(1);
#pragma unroll
    for (int ks = 0; ks < 2; ++ks) {
      int sw = ((ks * 4 + quad) ^ swz) * 8;
#pragma unroll
      for (int jf = 0; jf < 4; ++jf) {
        v8bf kf = *(v8bf*)&kshp[(jf * 16 + l15) * 64 + sw];
        s[0][jf] = __builtin_amdgcn_mfma_f32_16x16x32_bf16(kf, qf[0][ks], s[0][jf], 0, 0, 0);
        s[1][jf] = __builtin_amdgcn_mfma_f32_16x16x32_bf16(kf, qf[1][ks], s[1][jf], 0, 0, 0);
      }
    }
    __builtin_amdgcn_s_setprio(0);

    bool diag = (kt >= 2 * qi);
#pragma unroll
    for (int set = 0; set < 2; ++set) {
      int qrow = wave * 32 + set * 16 + l15;
      __bf16* prow = &psh[qrow * 64];
#pragma unroll
      for (int jf = 0; jf < 4; ++jf) {
        v4bf pk;
#pragma unroll
        for (int r = 0; r < 4; ++r) {
          float p = __builtin_amdgcn_exp2f(s[set][jf][r]);
          if (diag) {
            int kg = k0 + jf * 16 + quad * 4 + r;
            if (kg > qg[set]) p = 0.f;
          }
          pk[r] = (__bf16)p;
        }
        int chunk = jf * 2 + (quad >> 1);
        *(v4bf*)&prow[(chunk ^ swz) * 8 + (quad & 1) * 4] = pk;
      }
    }

    // O^T += V^T P^T ; lr += ones @ P^T (row sums, all lanes get full sum)
    __builtin_amdgcn_s_setprio(1);
#pragma unroll
    for (int ks = 0; ks < 2; ++ks) {
      int sw = ((ks * 4 + quad) ^ swz) * 8;
      v8bf pb0 = *(v8bf*)&psh[(wave * 32 + l15) * 64 + sw];
      v8bf pb1 = *(v8bf*)&psh[(wave * 32 + 16 + l15) * 64 + sw];
      lracc[0] = __builtin_amdgcn_mfma_f32_16x16x32_bf16(ones, pb0, lracc[0], 0, 0, 0);
      lracc[1] = __builtin_amdgcn_mfma_f32_16x16x32_bf16(ones, pb1, lracc[1], 0, 0, 0);
#pragma unroll
      for (int jm = 0; jm < 4; ++jm) {
        v8bf vf = *(v8bf*)&vshp[(jm * 16 + l15) * 64 + sw];
        oacc[0][jm] = __builtin_amdgcn_mfma_f32_16x16x32_bf16(vf, pb0, oacc[0][jm], 0, 0, 0);
        oacc[1][jm] = __builtin_amdgcn_mfma_f32_16x16x32_bf16(vf, pb1, oacc[1][jm], 0, 0, 0);
      }
    }
    __builtin_amdgcn_s_setprio(0);

    __builtin_amdgcn_s_waitcnt(0);   // own next-tile DMA long since done
    __syncthreads();
    pbuf ^= 1;
  }

  // epilogue: O[q][d] = O^T / lr
#pragma unroll
  for (int set = 0; set < 2; ++set) {
    float inv = 1.0f / lracc[set][0];
    int q = q0 + wave * 32 + set * 16 + l15;
#pragma unroll
    for (int jm = 0; jm < 4; ++jm) {
      v4bf o;
#pragma unroll
      for (int r = 0; r < 4; ++r) o[r] = (__bf16)(oacc[set][jm][r] * inv);
      *(v4bf*)(Ob + (size_t)q * DD + jm * 16 + quad * 4) = o;
    }
  }
}

// ---------------------------------------------------------------------------
extern "C" void kernel_launch(void* const* d_in, const int* in_sizes, int n_in,
                              void* d_out, int out_size, void* d_ws, size_t ws_size,
                              hipStream_t stream) {
  const float* query = (const float*)d_in[0];
  const float* key_  = (const float*)d_in[1];
  const float* value = (const float*)d_in[2];
  const float* wq_w = (const float*)d_in[3];
  const float* wq_b = (const float*)d_in[4];
  const float* wk_w = (const float*)d_in[5];
  const float* wk_b = (const float*)d_in[6];
  const float* wv_w = (const float*)d_in[7];
  const float* wv_b = (const float*)d_in[8];
  const float* wo_w = (const float*)d_in[9];
  const float* wo_b = (const float*)d_in[10];

  char* ws = (char*)d_ws;
  const size_t MB = (size_t)1 << 20;
  __bf16* wqT = (__bf16*)(ws + 0 * MB);
  __bf16* wkT = (__bf16*)(ws + 2 * MB);
  __bf16* wvT = (__bf16*)(ws + 4 * MB);
  __bf16* woT = (__bf16*)(ws + 6 * MB);
  __bf16* Qc  = (__bf16*)(ws + 8 * MB);    // cast inputs (later reused)
  __bf16* Kc  = (__bf16*)(ws + 24 * MB);
  __bf16* Vc  = (__bf16*)(ws + 40 * MB);
  __bf16* Qp  = (__bf16*)(ws + 56 * MB);
  __bf16* Kp  = (__bf16*)(ws + 72 * MB);
  __bf16* VTb = (__bf16*)(ws + 88 * MB);   // peak 104 MB
  __bf16* Ab  = (__bf16*)(ws + 8 * MB);    // reuse Qc
  float* out = (float*)d_out;

  dim3 tb(256);
  prep<<<dim3(2560), tb, 0, stream>>>(query, key_, value, wq_w, wk_w, wv_w, wo_w,
                                      Qc, Kc, Vc, wqT, wkT, wvT, woT);
  gemm_qkv<<<dim3(8, 64, 3), tb, 0, stream>>>(Qc, Kc, Vc, wqT, wkT, wvT,
                                              wq_b, wk_b, wv_b, Qp, Kp, VTb);
  attn_bal<<<dim3(8, 128), tb, 0, stream>>>(Qp, Kp, VTb, Ab);
  gemm_out<<<dim3(8, 64), tb, 0, stream>>>(Ab, woT, wo_b, out);
}